// Round 7
// baseline (151.003 us; speedup 1.0000x reference)
//
#include <hip/hip_runtime.h>

#define GAMMA 0.99f
#define LAM   0.95f

constexpr int WPB       = 4;          // waves (rows) per block
constexpr int BLOCK     = WPB * 64;
constexpr int PASS_COLS = 256;        // 64 lanes x 4 elements

// One WAVE per row, processed in T/256 backward passes of 256 columns.
// Lane owns 4 CONTIGUOUS elements per pass -> every load/store is a 1KB
// contiguous wave access (fixes R4's 128B-stride L1-thrash confound).
// No __syncthreads, no LDS, no inter-wave coupling: each wave streams
// continuously (3 loads + 2 stores per ~300cy pass), the rhythm measured
// LayerNorm kernels use to reach 82-86% of HBM BW on this chip.
//
// Backward linear recurrence g[t] = delta[t] + c[t]*g[t+1] via affine
// composition per pass: 4-deep per-thread compose -> 64-lane suffix scan
// -> replay; the pass total (lane 0's inclusive suffix) chains g across
// passes via two broadcasts.
__global__ __launch_bounds__(BLOCK) void gae_wave_kernel(
    const float* __restrict__ rewards,
    const float* __restrict__ values,
    const float* __restrict__ next_value,
    const int*   __restrict__ done,
    float* __restrict__ adv_out,
    float* __restrict__ ret_out,
    int B, int T)
{
    const int wave = threadIdx.x >> 6;
    const int lane = threadIdx.x & 63;
    const int row  = blockIdx.x * WPB + wave;
    if (row >= B) return;                        // wave-uniform

    const long rowbase = (long)row * T;
    const int  npass   = T / PASS_COLS;

    const float4* r4 = reinterpret_cast<const float4*>(rewards + rowbase);
    const float4* v4 = reinterpret_cast<const float4*>(values  + rowbase);
    const int4*   d4 = reinterpret_cast<const int4*>(done      + rowbase);
    float4* a4 = reinterpret_cast<float4*>(adv_out + rowbase);
    float4* t4 = reinterpret_cast<float4*>(ret_out + rowbase);

    const float vboot = next_value[row];         // wave-uniform scalar load

    auto LD = [&](int p, float4& R, float4& V, int4& D) {
        const int idx = p * 64 + lane;           // float4 index within row
        R = r4[idx]; V = v4[idx]; D = d4[idx];
    };

    // current / prefetched pass registers (all scalars -> no scratch)
    float4 cr, cv, nr, nv2;
    int4   cd, nd;
    LD(npass - 1, cr, cv, cd);

    float pv_bc = 0.0f;                          // pass(p+1) lane0 values.x
    float pd_bc = 0.0f;                          // pass(p+1) lane0 done.x
    float g     = 0.0f;                          // gae entering from the right

    for (int p = npass - 1; p >= 0; --p) {
        // ---- prefetch pass p-1 while computing pass p ----
        if (p > 0) LD(p - 1, nr, nv2, nd);

        const bool last = (p == npass - 1);

        // ---- boundary: values/done at col0+4 (lane+1's .x; lane 63 from
        //      the previously-processed pass's lane-0 broadcast / bootstrap)
        const float v_nb = __shfl_down(cv.x, 1);
        const int   d_nb = __shfl_down(cd.x, 1);
        float vnext  = (lane == 63) ? (last ? vboot : pv_bc) : v_nb;
        float dnextf = (lane == 63) ? (last ? (float)cd.w : pd_bc) : (float)d_nb;

        // ---- delta[t], c[t] for the 4 owned columns ----
        const float dn0 = (float)cd.y, dn1 = (float)cd.z, dn2 = (float)cd.w;
        float delta[4], c[4];
        {
            const float nnt0 = 1.0f - dn0;
            const float nnt1 = 1.0f - dn1;
            const float nnt2 = 1.0f - dn2;
            const float nnt3 = 1.0f - dnextf;
            delta[0] = cr.x + GAMMA * cv.y  * nnt0 - cv.x;
            delta[1] = cr.y + GAMMA * cv.z  * nnt1 - cv.y;
            delta[2] = cr.z + GAMMA * cv.w  * nnt2 - cv.z;
            delta[3] = cr.w + GAMMA * vnext * nnt3 - cv.w;
            c[0] = (GAMMA * LAM) * nnt0;
            c[1] = (GAMMA * LAM) * nnt1;
            c[2] = (GAMMA * LAM) * nnt2;
            c[3] = (GAMMA * LAM) * nnt3;
        }

        // ---- per-thread affine composition (backward over 4 cols) ----
        float a = 0.0f, m = 1.0f;
#pragma unroll
        for (int j = 3; j >= 0; --j) {
            a = delta[j] + c[j] * a;
            m = c[j] * m;
        }

        // ---- 64-lane inclusive SUFFIX scan (self ∘ higher-lane) ----
        float sa = a, sm = m;
#pragma unroll
        for (int dd = 1; dd < 64; dd <<= 1) {
            float oa = __shfl_down(sa, dd);
            float om = __shfl_down(sm, dd);
            if (lane + dd < 64) { sa = sa + sm * oa; sm = sm * om; }
        }
        float ea = __shfl_down(sa, 1);           // exclusive-within-wave
        float em = __shfl_down(sm, 1);
        if (lane == 63) { ea = 0.0f; em = 1.0f; }

        // ---- replay with the true incoming g ----
        float gin = ea + em * g;
#pragma unroll
        for (int j = 3; j >= 0; --j) {
            gin = delta[j] + c[j] * gin;
            delta[j] = gin;                      // delta[] now holds advantages
        }

        // ---- lane-contiguous stores ----
        const int idx = p * 64 + lane;
        a4[idx] = make_float4(delta[0], delta[1], delta[2], delta[3]);
        t4[idx] = make_float4(delta[0] + cv.x, delta[1] + cv.y,
                              delta[2] + cv.z, delta[3] + cv.w);

        // ---- chain to pass p-1: save lane-0 boundary, advance g ----
        pv_bc = __shfl(cv.x, 0);
        pd_bc = (float)__shfl(cd.x, 0);
        g     = __shfl(sa, 0) + __shfl(sm, 0) * g;

        cr = nr; cv = nv2; cd = nd;
    }
}

// Fallback for shapes where T % 256 != 0: one thread per row, sequential.
__global__ void gae_naive_kernel(
    const float* __restrict__ rewards,
    const float* __restrict__ values,
    const float* __restrict__ next_value,
    const int*   __restrict__ done,
    float* __restrict__ adv_out,
    float* __restrict__ ret_out,
    int B, int T)
{
    int row = blockIdx.x * blockDim.x + threadIdx.x;
    if (row >= B) return;
    long base = (long)row * T;
    float g = 0.0f;
    for (int t = T - 1; t >= 0; --t) {
        int dcol = (t + 1 < T) ? (t + 1) : (T - 1);
        float nnt = 1.0f - (float)done[base + dcol];
        float nv  = (t + 1 < T) ? values[base + t + 1] : next_value[row];
        float dl  = rewards[base + t] + GAMMA * nv * nnt - values[base + t];
        g = dl + (GAMMA * LAM) * nnt * g;
        adv_out[base + t] = g;
        ret_out[base + t] = g + values[base + t];
    }
}

extern "C" void kernel_launch(void* const* d_in, const int* in_sizes, int n_in,
                              void* d_out, int out_size, void* d_ws, size_t ws_size,
                              hipStream_t stream) {
    const float* rewards    = (const float*)d_in[0];
    const float* values     = (const float*)d_in[1];
    const float* next_value = (const float*)d_in[2];
    const int*   done       = (const int*)d_in[3];

    const int B = in_sizes[2];               // next_value is [B]
    const int T = in_sizes[0] / B;           // rewards is [B, T]

    float* adv = (float*)d_out;
    float* ret = adv + (long)B * T;

    if (T % PASS_COLS == 0 && T >= PASS_COLS) {
        const int grid = (B + WPB - 1) / WPB;
        gae_wave_kernel<<<grid, BLOCK, 0, stream>>>(
            rewards, values, next_value, done, adv, ret, B, T);
    } else {
        gae_naive_kernel<<<(B + 255) / 256, 256, 0, stream>>>(
            rewards, values, next_value, done, adv, ret, B, T);
    }
}